// Round 10
// baseline (294.297 us; speedup 1.0000x reference)
//
#include <hip/hip_runtime.h>

// VQ-VAE quantizer via MFMA: x[B=128,C=256,H=32,W=32] f32, e[K=512,C=256] f32.
// out[b,c,hw] = e[argmin_k ||z - e_k||^2][c].
//
// R10: barrier-free main loop. e is pre-swizzled (prep) into exact MFMA
// B-fragment order, so each wave's B-load is a per-lane contiguous dwordx4
// from L2 (e bf16 = 256KB, L2-resident per XCD). No LDS staging, no
// global_load_lds, no s_barrier/vmcnt asm -- waves fully independent, the
// compiler software-pipelines loads+MFMA (R5-R9: every barrier-synced DMA
// variant stalled at 170-200us regardless of chains/regs/A-build).
// Scores: 1-term bf16 (sc ~= ||e||^2 - 2 zh.eh), packed (score|code) top-3
// (R9), EPS=0.9; gap12<EPS -> fp64 pair compare; gap13<EPS -> fp64 full scan.
// Allocator law (R5/R8/R9): VGPR = min(demand, cap). Demand ~118 here, so
// __launch_bounds__(256,4) sets cap 128 -> no squeeze, no remat storm.

typedef __attribute__((ext_vector_type(8))) short bf16x8;
typedef __attribute__((ext_vector_type(4))) float f32x4;

constexpr int K_EMB = 512;
constexpr int C_DIM = 256;
constexpr int HW    = 1024;
constexpr float EPS_GAP = 0.9f;

// ws layout (bytes)
constexpr size_t WS_EBIAS = 64;                    // f32[512] (= ||e_k||^2 + 4096)
constexpr size_t WS_ESWZ  = 4096;                  // bf16 bits, B-frag order, 256KB
constexpr size_t WS_PAIR  = WS_ESWZ + 262144 + 64; // pair jobs: 2 ints each

__device__ __forceinline__ unsigned short f2bf(float f) {
    unsigned u = __float_as_uint(f);
    return (unsigned short)((u + 0x7FFFu + ((u >> 16) & 1u)) >> 16);
}

__device__ __forceinline__ float med3f(float a, float b, float c) {
    return fmaxf(fminf(a, b), fminf(fmaxf(a, b), c));
}

// ---- prep: e -> eSwz (B-fragment order) + (||e||^2 + 4096), zero counters --
// vq reads, per (nt, cs, lane, j): e[nt*16 + (lane&15)][cs*32 + (lane>>4)*8 + j]
// at bf16 offset ((nt*8+cs)*64 + lane)*8 + j.
__global__ __launch_bounds__(256) void prep_e(const float* __restrict__ e,
                                              unsigned short* __restrict__ eSwz,
                                              float* __restrict__ ebias,
                                              int* __restrict__ count) {
    const int k = blockIdx.x, c = threadIdx.x;
    if (k == 0 && c < 2) count[c] = 0;
    float v = e[(size_t)k * C_DIM + c];
    const int nt = k >> 4, lo = k & 15;
    const int cs = c >> 5, hi = (c >> 3) & 3, j = c & 7;
    eSwz[(((size_t)(nt * 8 + cs) * 64) + hi * 16 + lo) * 8 + j] = f2bf(v);

    __shared__ double red[256];
    red[c] = (double)v * (double)v;
    __syncthreads();
    for (int s = 128; s > 0; s >>= 1) {
        if (c < s) red[c] += red[c + s];
        __syncthreads();
    }
    if (c == 0) ebias[k] = (float)red[0] + 4096.0f;  // bias -> scores in one binade-pair
}

// ---- main: barrier-free 1-term GEMM + packed top-3 + fused gather ----
// Block = 4 waves x 32 rows = 128 rows. Grid = 1024.
__global__ __launch_bounds__(256, 4) void vq_mfma(const float* __restrict__ x,
                                                  const unsigned short* __restrict__ eSwz,
                                                  const float* __restrict__ ebias,
                                                  const float* __restrict__ e,
                                                  float* __restrict__ out,
                                                  int* __restrict__ count,
                                                  int* __restrict__ pairlist,
                                                  int paircap,
                                                  int* __restrict__ fulllist,
                                                  int fullcap) {
    __shared__ float eb_lds[512];
    __shared__ int idx_lds[128];
    const int t = threadIdx.x, lane = t & 63, w = t >> 6;
    const int b = blockIdx.x >> 3;
    const int hw0 = (blockIdx.x & 7) << 7;
    const float* xb = x + (size_t)b * C_DIM * HW;

    eb_lds[t]       = ebias[t];
    eb_lds[t + 256] = ebias[t + 256];

    // A fragments: lane holds A[m=lane&15][k=8*(lane>>4)+j], two 16-row m-frags
    bf16x8 Ah[2][8];
#pragma unroll
    for (int mf = 0; mf < 2; ++mf) {
        const int hw = hw0 + w * 32 + mf * 16 + (lane & 15);
#pragma unroll
        for (int cs = 0; cs < 8; ++cs) {
#pragma unroll
            for (int j = 0; j < 8; ++j) {
                int c = cs * 32 + ((lane >> 4) << 3) + j;
                Ah[mf][cs][j] = (short)f2bf(xb[(size_t)c * HW + hw]);
            }
        }
    }

    // packed top-3 per slot: t1 <= t2 <= t3, low 9 bits = code
    float t1[8], t2[8], t3[8];
#pragma unroll
    for (int s = 0; s < 8; ++s) { t1[s] = 1e30f; t2[s] = 1e30f; t3[s] = 1e30f; }

    __syncthreads();   // eb_lds ready (only pre-loop barrier)

    const unsigned short* ep = eSwz + (size_t)lane * 8;   // lane's frag column

#pragma unroll 1
    for (int nt = 0; nt < 32; ++nt) {
        f32x4 a0 = {0, 0, 0, 0}, a1 = {0, 0, 0, 0};
#pragma unroll
        for (int h = 0; h < 2; ++h) {
            bf16x8 Bf[4];
#pragma unroll
            for (int q = 0; q < 4; ++q)
                Bf[q] = *reinterpret_cast<const bf16x8*>(
                    ep + (size_t)(nt * 8 + h * 4 + q) * 512);   // coalesced L2 dwordx4
#pragma unroll
            for (int q = 0; q < 4; ++q) {
                a0 = __builtin_amdgcn_mfma_f32_16x16x32_bf16(Ah[0][h * 4 + q], Bf[q], a0, 0, 0, 0);
                a1 = __builtin_amdgcn_mfma_f32_16x16x32_bf16(Ah[1][h * 4 + q], Bf[q], a1, 0, 0, 0);
            }
        }

        const int code = nt * 16 + (lane & 15);
        const float eb = eb_lds[code];   // = ||e||^2 + 4096
#pragma unroll
        for (int mf = 0; mf < 2; ++mf) {
#pragma unroll
            for (int r = 0; r < 4; ++r) {
                float sc = fmaf(-2.f, (mf ? a1[r] : a0[r]), eb);   // in (2048, 8192)
                float sp = __uint_as_float((__float_as_uint(sc) & ~511u) | (unsigned)code);
                int s = mf * 4 + r;
                t3[s] = fminf(t3[s], fmaxf(t2[s], sp));   // branchless sorted insert
                t2[s] = fminf(fmaxf(sp, t1[s]), t2[s]);
                t1[s] = fminf(t1[s], sp);
            }
        }
    }

    // butterfly top-3 merge over the 16 col-lanes (packed => lexicographic)
#pragma unroll
    for (int m = 1; m < 16; m <<= 1) {
#pragma unroll
        for (int s = 0; s < 8; ++s) {
            float d  = __shfl_xor(t1[s], m);
            float e_ = __shfl_xor(t2[s], m);
            float f  = __shfl_xor(t3[s], m);
            float x1 = fminf(t1[s], d), y1 = fmaxf(t1[s], d);
            float x2 = fminf(t2[s], e_), y2 = fmaxf(t2[s], e_);
            float x3 = fminf(t3[s], f);
            t1[s] = x1;
            t2[s] = fminf(y1, x2);
            t3[s] = med3f(y1, x2, fminf(x3, y2));
        }
    }

    if ((lane & 15) == 0) {
#pragma unroll
        for (int s = 0; s < 8; ++s) {
            int row_local = (s >> 2) * 16 + ((lane >> 4) << 2) + (s & 3);
            int r = w * 32 + row_local;
            int bcode = (int)(__float_as_uint(t1[s]) & 511u);
            idx_lds[r] = bcode;
            int row = blockIdx.x * 128 + r;
            if (t3[s] - t1[s] < EPS_GAP) {                 // >=3 candidates: full scan
                int sl = atomicAdd(count + 1, 1);
                if (sl < fullcap) fulllist[sl] = row;
            } else if (t2[s] - t1[s] < EPS_GAP) {          // 2 candidates: pair job
                int scode = (int)(__float_as_uint(t2[s]) & 511u);
                int sl = atomicAdd(count, 1);
                if (sl < paircap) {
                    pairlist[2 * sl]     = row;
                    pairlist[2 * sl + 1] = (bcode << 16) | scode;
                }
            }
        }
    }
    __syncthreads();

    // fused gather: out[b,c,hw] = e[idx[j]][c]
    {
        const int j = t & 127;
        const int half = t >> 7;
        const int code = idx_lds[j];
        const float4* e4 = reinterpret_cast<const float4*>(e);
        float* ob = out + (size_t)b * C_DIM * HW + hw0 + j;
#pragma unroll
        for (int i = 0; i < 32; ++i) {
            int c4 = half * 32 + i;
            float4 v = e4[(size_t)code * 64 + c4];
            ob[(size_t)(c4 * 4 + 0) * HW] = v.x;
            ob[(size_t)(c4 * 4 + 1) * HW] = v.y;
            ob[(size_t)(c4 * 4 + 2) * HW] = v.z;
            ob[(size_t)(c4 * 4 + 3) * HW] = v.w;
        }
    }
}

// ---- pair_refine: exact fp64 compare of 2 candidate codes; 4 jobs/block ----
__global__ __launch_bounds__(256) void pair_refine(const float* __restrict__ x,
                                                   const float* __restrict__ e,
                                                   float* __restrict__ out,
                                                   const int* __restrict__ pairlist,
                                                   const int* __restrict__ count,
                                                   int paircap) {
    int njobs = count[0]; if (njobs > paircap) njobs = paircap;
    const int lane = threadIdx.x & 63, w = threadIdx.x >> 6;

    for (int job = blockIdx.x * 4 + w; job < njobs; job += gridDim.x * 4) {
        const int row = pairlist[2 * job];
        const int ab  = pairlist[2 * job + 1];
        const int a = ab >> 16, b2 = ab & 0xffff;
        const float* xb = x + (size_t)(row >> 10) * (C_DIM * HW) + (row & 1023);

        const float4 ea = reinterpret_cast<const float4*>(e + (size_t)a  * C_DIM)[lane];
        const float4 eb = reinterpret_cast<const float4*>(e + (size_t)b2 * C_DIM)[lane];
        float z0 = xb[(size_t)(lane * 4 + 0) * HW];
        float z1 = xb[(size_t)(lane * 4 + 1) * HW];
        float z2 = xb[(size_t)(lane * 4 + 2) * HW];
        float z3 = xb[(size_t)(lane * 4 + 3) * HW];

        double da = 0.0, db = 0.0, df;
        df = (double)z0 - ea.x; da = fma(df, df, da);
        df = (double)z1 - ea.y; da = fma(df, df, da);
        df = (double)z2 - ea.z; da = fma(df, df, da);
        df = (double)z3 - ea.w; da = fma(df, df, da);
        df = (double)z0 - eb.x; db = fma(df, df, db);
        df = (double)z1 - eb.y; db = fma(df, df, db);
        df = (double)z2 - eb.z; db = fma(df, df, db);
        df = (double)z3 - eb.w; db = fma(df, df, db);
#pragma unroll
        for (int off = 1; off < 64; off <<= 1) {
            da += __shfl_xor(da, off);
            db += __shfl_xor(db, off);
        }
        const int winner = (da < db || (da == db && a < b2)) ? a : b2;
        if (winner != a) {   // vq already wrote e[a]; rewrite only on flip
            const float4 ew = reinterpret_cast<const float4*>(e + (size_t)winner * C_DIM)[lane];
            float* ob = out + (size_t)(row >> 10) * (C_DIM * HW) + (row & 1023);
            ob[(size_t)(lane * 4 + 0) * HW] = ew.x;
            ob[(size_t)(lane * 4 + 1) * HW] = ew.y;
            ob[(size_t)(lane * 4 + 2) * HW] = ew.z;
            ob[(size_t)(lane * 4 + 3) * HW] = ew.w;
        }
    }
}

// ---- full_refine: exact fp64 scan of all 512 codes (rare); 1 wave/block ----
__global__ __launch_bounds__(64) void full_refine(const float* __restrict__ x,
                                                  const float* __restrict__ e,
                                                  float* __restrict__ out,
                                                  const int* __restrict__ fulllist,
                                                  const int* __restrict__ count,
                                                  int fullcap) {
    __shared__ float zs[C_DIM];
    int njobs = count[1]; if (njobs > fullcap) njobs = fullcap;
    const int lane = threadIdx.x;

    for (int job = blockIdx.x; job < njobs; job += gridDim.x) {
        const int row = fulllist[job];
        const float* xb = x + (size_t)(row >> 10) * (C_DIM * HW) + (row & 1023);
#pragma unroll
        for (int i = 0; i < 4; ++i) {
            int c = lane + 64 * i;
            zs[c] = xb[(size_t)c * HW];
        }
        __syncthreads();

        double d[8];
#pragma unroll
        for (int i = 0; i < 8; ++i) d[i] = 0.0;
#pragma unroll 2
        for (int c4 = 0; c4 < 64; ++c4) {
            const float4 z4 = reinterpret_cast<const float4*>(zs)[c4];
#pragma unroll
            for (int i = 0; i < 8; ++i) {   // 8 independent fp64 chains
                const float4 ev = reinterpret_cast<const float4*>(
                    e + (size_t)(lane + 64 * i) * C_DIM)[c4];
                double df;
                df = (double)z4.x - ev.x; d[i] = fma(df, df, d[i]);
                df = (double)z4.y - ev.y; d[i] = fma(df, df, d[i]);
                df = (double)z4.z - ev.z; d[i] = fma(df, df, d[i]);
                df = (double)z4.w - ev.w; d[i] = fma(df, df, d[i]);
            }
        }
        double bd = d[0]; int bk = lane;
#pragma unroll
        for (int i = 1; i < 8; ++i)
            if (d[i] < bd) { bd = d[i]; bk = lane + 64 * i; }
#pragma unroll
        for (int off = 1; off < 64; off <<= 1) {
            double od = __shfl_xor(bd, off);
            int    ok = __shfl_xor(bk, off);
            if (od < bd || (od == bd && ok < bk)) { bd = od; bk = ok; }
        }
        const float4 ew = reinterpret_cast<const float4*>(e + (size_t)bk * C_DIM)[lane];
        float* ob = out + (size_t)(row >> 10) * (C_DIM * HW) + (row & 1023);
        ob[(size_t)(lane * 4 + 0) * HW] = ew.x;
        ob[(size_t)(lane * 4 + 1) * HW] = ew.y;
        ob[(size_t)(lane * 4 + 2) * HW] = ew.z;
        ob[(size_t)(lane * 4 + 3) * HW] = ew.w;
        __syncthreads();
    }
}

extern "C" void kernel_launch(void* const* d_in, const int* in_sizes, int n_in,
                              void* d_out, int out_size, void* d_ws, size_t ws_size,
                              hipStream_t stream) {
    const float* x = (const float*)d_in[0];
    const float* e = (const float*)d_in[1];
    float* out = (float*)d_out;

    char* ws = (char*)d_ws;
    int* count = (int*)ws;                       // [0]=pair, [1]=full
    float* ebias = (float*)(ws + WS_EBIAS);
    unsigned short* eSwz = (unsigned short*)(ws + WS_ESWZ);
    int* pairlist = (int*)(ws + WS_PAIR);

    int paircap = 0, fullcap = 0;
    if (ws_size > WS_PAIR + 64) {
        size_t avail = ws_size - WS_PAIR;
        size_t pc = (avail * 2 / 3) / 8;         // 2 ints per pair job
        paircap = (int)(pc > 49152 ? 49152 : pc);
        size_t rem = avail - (size_t)paircap * 8;
        size_t fc = rem / 4;
        fullcap = (int)(fc > 16384 ? 16384 : fc);
    }
    int* fulllist = pairlist + 2 * (size_t)paircap;

    const int B = in_sizes[0] / (C_DIM * HW);

    hipLaunchKernelGGL(prep_e, dim3(K_EMB), dim3(256), 0, stream, e, eSwz, ebias, count);
    hipLaunchKernelGGL(vq_mfma, dim3(B * 8), dim3(256), 0, stream,
                       x, eSwz, ebias, e, out, count, pairlist, paircap, fulllist, fullcap);
    hipLaunchKernelGGL(pair_refine, dim3(2048), dim3(256), 0, stream,
                       x, e, out, pairlist, count, paircap);
    hipLaunchKernelGGL(full_refine, dim3(1024), dim3(64), 0, stream,
                       x, e, out, fulllist, count, fullcap);
}

// Round 11
// 267.251 us; speedup vs baseline: 1.1012x; 1.1012x over previous
//
#include <hip/hip_runtime.h>

// VQ-VAE quantizer via MFMA: x[B=128,C=256,H=32,W=32] f32, e[K=512,C=256] f32.
// out[b,c,hw] = e[argmin_k ||z - e_k||^2][c].
//
// R11: the R5-R10 ~200us plateau = allocator squeeze (VGPR 56-84 vs ~112
// demand; launch_bounds' 2nd arg is only a MIN waves/EU) destroying ILP, so
// every B-load -> MFMA pays full L2 latency serialized. Fixes:
//  - amdgpu_waves_per_eu(4,4): pins register budget at 128 -> no squeeze.
//  - B-operands from LDS (fragment-linear eSwz staged in 16KB segments via
//    global_load_lds; contiguous ds_read_b128, conflict-free, no swizzle),
//    ~12cyc latency the compiler can pipeline. Two plain __syncthreads per
//    segment (compiler auto-drains vmcnt/lgkmcnt -- no inline asm).
//  - 128-thread blocks, grid 2048, LDS 18.7KB -> 8 blocks/CU: whole grid
//    resident in one batch (16 waves/CU), zero dispatch tail.
// Scores: 1-term bf16 (sc ~= ||e||^2 - 2 zh.eh), packed (score|code) top-3,
// EPS=0.9 (R9/R10-proven); gap12<EPS -> fp64 pair compare; gap13<EPS ->
// fp64 full scan.

typedef __attribute__((ext_vector_type(8))) short bf16x8;
typedef __attribute__((ext_vector_type(4))) float f32x4;

constexpr int K_EMB = 512;
constexpr int C_DIM = 256;
constexpr int HW    = 1024;
constexpr float EPS_GAP = 0.9f;

// ws layout (bytes)
constexpr size_t WS_EBIAS = 64;                    // f32[512] (= ||e_k||^2 + 4096)
constexpr size_t WS_ESWZ  = 4096;                  // bf16 bits, B-frag order, 256KB
constexpr size_t WS_PAIR  = WS_ESWZ + 262144 + 64; // pair jobs: 2 ints each

__device__ __forceinline__ unsigned short f2bf(float f) {
    unsigned u = __float_as_uint(f);
    return (unsigned short)((u + 0x7FFFu + ((u >> 16) & 1u)) >> 16);
}

__device__ __forceinline__ float med3f(float a, float b, float c) {
    return fmaxf(fminf(a, b), fminf(fmaxf(a, b), c));
}

// ---- prep: e -> eSwz (B-fragment order) + (||e||^2 + 4096), zero counters --
// vq reads, per (nt, cs, lane, j): e[nt*16 + (lane&15)][cs*32 + (lane>>4)*8 + j]
// at byte offset (nt*8+cs)*1024 + lane*16 + j*2.   (R10-verified, absmax 0)
__global__ __launch_bounds__(256) void prep_e(const float* __restrict__ e,
                                              unsigned short* __restrict__ eSwz,
                                              float* __restrict__ ebias,
                                              int* __restrict__ count) {
    const int k = blockIdx.x, c = threadIdx.x;
    if (k == 0 && c < 2) count[c] = 0;
    float v = e[(size_t)k * C_DIM + c];
    const int nt = k >> 4, lo = k & 15;
    const int cs = c >> 5, hi = (c >> 3) & 3, j = c & 7;
    eSwz[(((size_t)(nt * 8 + cs) * 64) + hi * 16 + lo) * 8 + j] = f2bf(v);

    __shared__ double red[256];
    red[c] = (double)v * (double)v;
    __syncthreads();
    for (int s = 128; s > 0; s >>= 1) {
        if (c < s) red[c] += red[c + s];
        __syncthreads();
    }
    if (c == 0) ebias[k] = (float)red[0] + 4096.0f;  // scores land in one binade-pair
}

// ---- stage one 16KB segment (2 nt-tiles) into LDS; wave w covers 8x1KB ----
// eSwz is fragment-linear, so source AND LDS are plain linear copies.
__device__ __forceinline__ void stage_seg(char* seg, const char* eswzB, int s,
                                          int w, int lane) {
#pragma unroll
    for (int r = 0; r < 8; ++r) {
        int off = (w * 8 + r) * 1024;
        __builtin_amdgcn_global_load_lds(
            (const __attribute__((address_space(1))) unsigned int*)
                (eswzB + (size_t)s * 16384 + off + lane * 16),
            (__attribute__((address_space(3))) unsigned int*)(seg + off), 16, 0, 0);
    }
}

// ---- main: LDS-B 1-term GEMM + packed top-3 + fused gather ----
// Block = 2 waves x 32 rows = 64 rows. Grid = 2048 (whole grid resident:
// 8 blocks/CU x 18.7KB LDS, 16 waves/CU).
__global__ __attribute__((amdgpu_waves_per_eu(4, 4))) __launch_bounds__(128)
void vq_mfma(const float* __restrict__ x,
             const unsigned short* __restrict__ eSwz,
             const float* __restrict__ ebias,
             const float* __restrict__ e,
             float* __restrict__ out,
             int* __restrict__ count,
             int* __restrict__ pairlist,
             int paircap,
             int* __restrict__ fulllist,
             int fullcap) {
    __shared__ __align__(16) char seg[16384];
    __shared__ float eb_lds[512];
    __shared__ int idx_lds[64];
    const int t = threadIdx.x, lane = t & 63, w = t >> 6;   // w in {0,1}
    const int b = blockIdx.x >> 4;
    const int hw0 = (blockIdx.x & 15) << 6;
    const float* xb = x + (size_t)b * C_DIM * HW;
    const char* eswzB = (const char*)eSwz;

    // stage segment 0 (latency hides under A-build)
    stage_seg(seg, eswzB, 0, w, lane);

    // ebias -> LDS
#pragma unroll
    for (int i = 0; i < 4; ++i) eb_lds[t + 128 * i] = ebias[t + 128 * i];

    // A fragments: lane holds A[m=lane&15][k=8*(lane>>4)+j], two 16-row m-frags
    bf16x8 Ah[2][8];
#pragma unroll
    for (int mf = 0; mf < 2; ++mf) {
        const int hw = hw0 + w * 32 + mf * 16 + (lane & 15);
#pragma unroll
        for (int cs = 0; cs < 8; ++cs) {
#pragma unroll
            for (int j = 0; j < 8; ++j) {
                int c = cs * 32 + ((lane >> 4) << 3) + j;
                Ah[mf][cs][j] = (short)f2bf(xb[(size_t)c * HW + hw]);
            }
        }
    }

    // packed top-3 per slot: t1 <= t2 <= t3, low 9 bits = code
    float t1[8], t2[8], t3[8];
#pragma unroll
    for (int s = 0; s < 8; ++s) { t1[s] = 1e30f; t2[s] = 1e30f; t3[s] = 1e30f; }

    __syncthreads();   // drains segment-0 DMA + eb_lds writes

#pragma unroll 1
    for (int s = 0; s < 16; ++s) {
#pragma unroll
        for (int ln = 0; ln < 2; ++ln) {
            const int nt = s * 2 + ln;
            f32x4 a0 = {0, 0, 0, 0}, a1 = {0, 0, 0, 0};
#pragma unroll
            for (int q = 0; q < 8; ++q) {
                bf16x8 Bh = *reinterpret_cast<const bf16x8*>(
                    seg + (ln * 8 + q) * 1024 + lane * 16);   // contiguous b128
                a0 = __builtin_amdgcn_mfma_f32_16x16x32_bf16(Ah[0][q], Bh, a0, 0, 0, 0);
                a1 = __builtin_amdgcn_mfma_f32_16x16x32_bf16(Ah[1][q], Bh, a1, 0, 0, 0);
            }
            const int code = nt * 16 + (lane & 15);
            const float eb = eb_lds[code];   // = ||e||^2 + 4096
#pragma unroll
            for (int mf = 0; mf < 2; ++mf) {
#pragma unroll
                for (int r = 0; r < 4; ++r) {
                    float sc = fmaf(-2.f, (mf ? a1[r] : a0[r]), eb);
                    float sp = __uint_as_float((__float_as_uint(sc) & ~511u) | (unsigned)code);
                    int sl = mf * 4 + r;
                    t3[sl] = fminf(t3[sl], fmaxf(t2[sl], sp));   // branchless sorted insert
                    t2[sl] = fminf(fmaxf(sp, t1[sl]), t2[sl]);
                    t1[sl] = fminf(t1[sl], sp);
                }
            }
        }
        __syncthreads();                        // all waves done reading seg
        if (s < 15) stage_seg(seg, eswzB, s + 1, w, lane);
        __syncthreads();                        // seg ready (drains vmcnt)
    }

    // butterfly top-3 merge over the 16 col-lanes (packed => lexicographic)
#pragma unroll
    for (int m = 1; m < 16; m <<= 1) {
#pragma unroll
        for (int s = 0; s < 8; ++s) {
            float d  = __shfl_xor(t1[s], m);
            float e_ = __shfl_xor(t2[s], m);
            float f  = __shfl_xor(t3[s], m);
            float x1 = fminf(t1[s], d), y1 = fmaxf(t1[s], d);
            float x2 = fminf(t2[s], e_), y2 = fmaxf(t2[s], e_);
            float x3 = fminf(t3[s], f);
            t1[s] = x1;
            t2[s] = fminf(y1, x2);
            t3[s] = med3f(y1, x2, fminf(x3, y2));
        }
    }

    if ((lane & 15) == 0) {
#pragma unroll
        for (int s = 0; s < 8; ++s) {
            int rl = (s >> 2) * 16 + ((lane >> 4) << 2) + (s & 3);
            int r = w * 32 + rl;
            int bcode = (int)(__float_as_uint(t1[s]) & 511u);
            idx_lds[r] = bcode;
            int row = blockIdx.x * 64 + r;
            if (t3[s] - t1[s] < EPS_GAP) {                 // >=3 candidates: full scan
                int sl = atomicAdd(count + 1, 1);
                if (sl < fullcap) fulllist[sl] = row;
            } else if (t2[s] - t1[s] < EPS_GAP) {          // 2 candidates: pair job
                int scode = (int)(__float_as_uint(t2[s]) & 511u);
                int sl = atomicAdd(count, 1);
                if (sl < paircap) {
                    pairlist[2 * sl]     = row;
                    pairlist[2 * sl + 1] = (bcode << 16) | scode;
                }
            }
        }
    }
    __syncthreads();

    // fused gather: out[b,c,hw] = e[idx[j]][c]
    {
        const int j = t & 63;
        const int half = t >> 6;
        const int code = idx_lds[j];
        const float4* e4 = reinterpret_cast<const float4*>(e);
        float* ob = out + (size_t)b * C_DIM * HW + hw0 + j;
#pragma unroll
        for (int i = 0; i < 32; ++i) {
            int c4 = half * 32 + i;
            float4 v = e4[(size_t)code * 64 + c4];
            ob[(size_t)(c4 * 4 + 0) * HW] = v.x;
            ob[(size_t)(c4 * 4 + 1) * HW] = v.y;
            ob[(size_t)(c4 * 4 + 2) * HW] = v.z;
            ob[(size_t)(c4 * 4 + 3) * HW] = v.w;
        }
    }
}

// ---- pair_refine: exact fp64 compare of 2 candidate codes; 4 jobs/block ----
__global__ __launch_bounds__(256) void pair_refine(const float* __restrict__ x,
                                                   const float* __restrict__ e,
                                                   float* __restrict__ out,
                                                   const int* __restrict__ pairlist,
                                                   const int* __restrict__ count,
                                                   int paircap) {
    int njobs = count[0]; if (njobs > paircap) njobs = paircap;
    const int lane = threadIdx.x & 63, w = threadIdx.x >> 6;

    for (int job = blockIdx.x * 4 + w; job < njobs; job += gridDim.x * 4) {
        const int row = pairlist[2 * job];
        const int ab  = pairlist[2 * job + 1];
        const int a = ab >> 16, b2 = ab & 0xffff;
        const float* xb = x + (size_t)(row >> 10) * (C_DIM * HW) + (row & 1023);

        const float4 ea = reinterpret_cast<const float4*>(e + (size_t)a  * C_DIM)[lane];
        const float4 eb = reinterpret_cast<const float4*>(e + (size_t)b2 * C_DIM)[lane];
        float z0 = xb[(size_t)(lane * 4 + 0) * HW];
        float z1 = xb[(size_t)(lane * 4 + 1) * HW];
        float z2 = xb[(size_t)(lane * 4 + 2) * HW];
        float z3 = xb[(size_t)(lane * 4 + 3) * HW];

        double da = 0.0, db = 0.0, df;
        df = (double)z0 - ea.x; da = fma(df, df, da);
        df = (double)z1 - ea.y; da = fma(df, df, da);
        df = (double)z2 - ea.z; da = fma(df, df, da);
        df = (double)z3 - ea.w; da = fma(df, df, da);
        df = (double)z0 - eb.x; db = fma(df, df, db);
        df = (double)z1 - eb.y; db = fma(df, df, db);
        df = (double)z2 - eb.z; db = fma(df, df, db);
        df = (double)z3 - eb.w; db = fma(df, df, db);
#pragma unroll
        for (int off = 1; off < 64; off <<= 1) {
            da += __shfl_xor(da, off);
            db += __shfl_xor(db, off);
        }
        const int winner = (da < db || (da == db && a < b2)) ? a : b2;
        if (winner != a) {   // vq already wrote e[a]; rewrite only on flip
            const float4 ew = reinterpret_cast<const float4*>(e + (size_t)winner * C_DIM)[lane];
            float* ob = out + (size_t)(row >> 10) * (C_DIM * HW) + (row & 1023);
            ob[(size_t)(lane * 4 + 0) * HW] = ew.x;
            ob[(size_t)(lane * 4 + 1) * HW] = ew.y;
            ob[(size_t)(lane * 4 + 2) * HW] = ew.z;
            ob[(size_t)(lane * 4 + 3) * HW] = ew.w;
        }
    }
}

// ---- full_refine: exact fp64 scan of all 512 codes (rare); 1 wave/block ----
__global__ __launch_bounds__(64) void full_refine(const float* __restrict__ x,
                                                  const float* __restrict__ e,
                                                  float* __restrict__ out,
                                                  const int* __restrict__ fulllist,
                                                  const int* __restrict__ count,
                                                  int fullcap) {
    __shared__ float zs[C_DIM];
    int njobs = count[1]; if (njobs > fullcap) njobs = fullcap;
    const int lane = threadIdx.x;

    for (int job = blockIdx.x; job < njobs; job += gridDim.x) {
        const int row = fulllist[job];
        const float* xb = x + (size_t)(row >> 10) * (C_DIM * HW) + (row & 1023);
#pragma unroll
        for (int i = 0; i < 4; ++i) {
            int c = lane + 64 * i;
            zs[c] = xb[(size_t)c * HW];
        }
        __syncthreads();

        double d[8];
#pragma unroll
        for (int i = 0; i < 8; ++i) d[i] = 0.0;
#pragma unroll 2
        for (int c4 = 0; c4 < 64; ++c4) {
            const float4 z4 = reinterpret_cast<const float4*>(zs)[c4];
#pragma unroll
            for (int i = 0; i < 8; ++i) {   // 8 independent fp64 chains
                const float4 ev = reinterpret_cast<const float4*>(
                    e + (size_t)(lane + 64 * i) * C_DIM)[c4];
                double df;
                df = (double)z4.x - ev.x; d[i] = fma(df, df, d[i]);
                df = (double)z4.y - ev.y; d[i] = fma(df, df, d[i]);
                df = (double)z4.z - ev.z; d[i] = fma(df, df, d[i]);
                df = (double)z4.w - ev.w; d[i] = fma(df, df, d[i]);
            }
        }
        double bd = d[0]; int bk = lane;
#pragma unroll
        for (int i = 1; i < 8; ++i)
            if (d[i] < bd) { bd = d[i]; bk = lane + 64 * i; }
#pragma unroll
        for (int off = 1; off < 64; off <<= 1) {
            double od = __shfl_xor(bd, off);
            int    ok = __shfl_xor(bk, off);
            if (od < bd || (od == bd && ok < bk)) { bd = od; bk = ok; }
        }
        const float4 ew = reinterpret_cast<const float4*>(e + (size_t)bk * C_DIM)[lane];
        float* ob = out + (size_t)(row >> 10) * (C_DIM * HW) + (row & 1023);
        ob[(size_t)(lane * 4 + 0) * HW] = ew.x;
        ob[(size_t)(lane * 4 + 1) * HW] = ew.y;
        ob[(size_t)(lane * 4 + 2) * HW] = ew.z;
        ob[(size_t)(lane * 4 + 3) * HW] = ew.w;
        __syncthreads();
    }
}

extern "C" void kernel_launch(void* const* d_in, const int* in_sizes, int n_in,
                              void* d_out, int out_size, void* d_ws, size_t ws_size,
                              hipStream_t stream) {
    const float* x = (const float*)d_in[0];
    const float* e = (const float*)d_in[1];
    float* out = (float*)d_out;

    char* ws = (char*)d_ws;
    int* count = (int*)ws;                       // [0]=pair, [1]=full
    float* ebias = (float*)(ws + WS_EBIAS);
    unsigned short* eSwz = (unsigned short*)(ws + WS_ESWZ);
    int* pairlist = (int*)(ws + WS_PAIR);

    int paircap = 0, fullcap = 0;
    if (ws_size > WS_PAIR + 64) {
        size_t avail = ws_size - WS_PAIR;
        size_t pc = (avail * 2 / 3) / 8;         // 2 ints per pair job
        paircap = (int)(pc > 49152 ? 49152 : pc);
        size_t rem = avail - (size_t)paircap * 8;
        size_t fc = rem / 4;
        fullcap = (int)(fc > 16384 ? 16384 : fc);
    }
    int* fulllist = pairlist + 2 * (size_t)paircap;

    const int B = in_sizes[0] / (C_DIM * HW);

    hipLaunchKernelGGL(prep_e, dim3(K_EMB), dim3(256), 0, stream, e, eSwz, ebias, count);
    hipLaunchKernelGGL(vq_mfma, dim3(B * 16), dim3(128), 0, stream,
                       x, eSwz, ebias, e, out, count, pairlist, paircap, fulllist, fullcap);
    hipLaunchKernelGGL(pair_refine, dim3(1024), dim3(256), 0, stream,
                       x, e, out, pairlist, count, paircap);
    hipLaunchKernelGGL(full_refine, dim3(2048), dim3(64), 0, stream,
                       x, e, out, fulllist, count, fullcap);
}